// Round 2
// baseline (1218.628 us; speedup 1.0000x reference)
//
#include <hip/hip_runtime.h>
#include <hip/hip_bf16.h>

#define FEAT 256
#define HID 128
#define CLASSES 32
#define LAYERS 3

// x = relu(feat @ emb_w + emb_b)   [N,256]@[256,128]
__global__ void embed_kernel(const float* __restrict__ feat, const float* __restrict__ w,
                             const float* __restrict__ b, float* __restrict__ x) {
    int n = blockIdx.x;
    int h = threadIdx.x;  // 0..127
    __shared__ float s_a[FEAT];
    s_a[h]       = feat[(size_t)n * FEAT + h];
    s_a[h + 128] = feat[(size_t)n * FEAT + h + 128];
    __syncthreads();
    float acc = b[h];
#pragma unroll 8
    for (int k = 0; k < FEAT; ++k)
        acc += s_a[k] * w[k * HID + h];
    x[(size_t)n * HID + h] = fmaxf(acc, 0.f);
}

__global__ void count_kernel(const int* __restrict__ dst, int* __restrict__ counts, int E) {
    int e = blockIdx.x * blockDim.x + threadIdx.x;
    if (e < E) atomicAdd(&counts[dst[e]], 1);
}

// single-block exclusive scan over counts[N] -> row_off[N+1], cursor[N]
__global__ void scan_kernel(const int* __restrict__ counts, int* __restrict__ row_off,
                            int* __restrict__ cursor, int N) {
    __shared__ int s[1024];
    int t = threadIdx.x;
    int carry = 0;
    for (int base = 0; base < N; base += 1024) {
        int v = (base + t < N) ? counts[base + t] : 0;
        s[t] = v;
        __syncthreads();
        for (int off = 1; off < 1024; off <<= 1) {
            int add = (t >= off) ? s[t - off] : 0;
            __syncthreads();
            s[t] += add;
            __syncthreads();
        }
        int excl = s[t] - v;
        if (base + t < N) { row_off[base + t] = carry + excl; cursor[base + t] = carry + excl; }
        int tot = s[1023];
        __syncthreads();
        carry += tot;
    }
    if (t == 0) row_off[N] = carry;
}

__global__ void fill_kernel(const int* __restrict__ src, const int* __restrict__ dst,
                            int* __restrict__ cursor, int* __restrict__ csr_src, int E) {
    int e = blockIdx.x * blockDim.x + threadIdx.x;
    if (e < E) {
        int pos = atomicAdd(&cursor[dst[e]], 1);
        csr_src[pos] = src[e];
    }
}

// x_out = relu( (sum_{j in in(n)} x_in[j]) @ rel_w + rel_b + x_in[n] @ root_w )
__global__ void layer_kernel(const float* __restrict__ x_in, float* __restrict__ x_out,
                             const int* __restrict__ row_off, const int* __restrict__ csr_src,
                             const float* __restrict__ rel_w, const float* __restrict__ rel_b,
                             const float* __restrict__ root_w) {
    int n = blockIdx.x;
    int h = threadIdx.x;  // 0..127
    __shared__ float s_agg[HID];
    __shared__ float s_x[HID];
    int beg = row_off[n], end = row_off[n + 1];
    float a = 0.f;
    for (int j = beg; j < end; ++j)
        a += x_in[(size_t)csr_src[j] * HID + h];
    s_agg[h] = a;
    s_x[h] = x_in[(size_t)n * HID + h];
    __syncthreads();
    float acc = rel_b[h];
#pragma unroll 8
    for (int k = 0; k < HID; ++k)
        acc += s_agg[k] * rel_w[k * HID + h] + s_x[k] * root_w[k * HID + h];
    x_out[(size_t)n * HID + h] = fmaxf(acc, 0.f);
}

// ps = x @ head_w[:128], pd = x @ head_w[128:]   per node
__global__ void proj_kernel(const float* __restrict__ x, const float* __restrict__ head_w,
                            float* __restrict__ ps, float* __restrict__ pd) {
    int n = blockIdx.x;
    int t = threadIdx.x;  // 0..63 (one wave)
    __shared__ float s_x[HID];
    s_x[t]      = x[(size_t)n * HID + t];
    s_x[t + 64] = x[(size_t)n * HID + t + 64];
    __syncthreads();
    int c = t & 31;
    const float* w = head_w + ((t < 32) ? 0 : (size_t)HID * CLASSES);
    float acc = 0.f;
#pragma unroll 8
    for (int k = 0; k < HID; ++k)
        acc += s_x[k] * w[k * CLASSES + c];
    if (t < 32) ps[(size_t)n * CLASSES + c] = acc;
    else        pd[(size_t)n * CLASSES + c] = acc;
}

// out[e][c] = ps[src[e]][c] + pd[dst[e]][c] + head_b[c]
__global__ void edge_out_kernel(const int* __restrict__ src, const int* __restrict__ dst,
                                const float* __restrict__ ps, const float* __restrict__ pd,
                                const float* __restrict__ head_b, float* __restrict__ out, int E) {
    int idx = blockIdx.x * blockDim.x + threadIdx.x;
    int e = idx >> 5;
    int c = idx & 31;
    if (e < E) {
        float v = ps[(size_t)src[e] * CLASSES + c] + pd[(size_t)dst[e] * CLASSES + c] + head_b[c];
        out[(size_t)e * CLASSES + c] = v;
    }
}

extern "C" void kernel_launch(void* const* d_in, const int* in_sizes, int n_in,
                              void* d_out, int out_size, void* d_ws, size_t ws_size,
                              hipStream_t stream) {
    const float* feat   = (const float*)d_in[0];
    const int*   eidx   = (const int*)d_in[1];
    const float* emb_w  = (const float*)d_in[2];
    const float* emb_b  = (const float*)d_in[3];
    const float* rel_w  = (const float*)d_in[4];
    const float* rel_b  = (const float*)d_in[5];
    const float* root_w = (const float*)d_in[6];
    const float* head_w = (const float*)d_in[7];
    const float* head_b = (const float*)d_in[8];
    float* out = (float*)d_out;

    int N = in_sizes[0] / FEAT;
    int E = in_sizes[1] / 2;
    const int* src = eidx;
    const int* dst = eidx + E;

    // workspace layout
    float* xA      = (float*)d_ws;                      // N*HID
    float* xB      = xA + (size_t)N * HID;              // N*HID
    float* ps      = xB + (size_t)N * HID;              // N*CLASSES
    float* pd      = ps + (size_t)N * CLASSES;          // N*CLASSES
    int*   counts  = (int*)(pd + (size_t)N * CLASSES);  // N
    int*   row_off = counts + N;                        // N+1
    int*   cursor  = row_off + (N + 1);                 // N
    int*   csr_src = cursor + N;                        // E

    hipMemsetAsync(counts, 0, (size_t)N * sizeof(int), stream);
    count_kernel<<<(E + 255) / 256, 256, 0, stream>>>(dst, counts, E);
    scan_kernel<<<1, 1024, 0, stream>>>(counts, row_off, cursor, N);
    fill_kernel<<<(E + 255) / 256, 256, 0, stream>>>(src, dst, cursor, csr_src, E);

    embed_kernel<<<N, HID, 0, stream>>>(feat, emb_w, emb_b, xA);

    const float* xin = xA;
    float* xout = xB;
    for (int l = 0; l < LAYERS; ++l) {
        layer_kernel<<<N, HID, 0, stream>>>(xin, xout, row_off, csr_src,
                                            rel_w + (size_t)l * HID * HID,
                                            rel_b + (size_t)l * HID,
                                            root_w + (size_t)l * HID * HID);
        float* tmp = (float*)xin; xin = xout; xout = tmp;
    }

    proj_kernel<<<N, 64, 0, stream>>>(xin, head_w, ps, pd);
    edge_out_kernel<<<((size_t)E * 32 + 255) / 256, 256, 0, stream>>>(src, dst, ps, pd, head_b, out, E);
}

// Round 3
// 848.026 us; speedup vs baseline: 1.4370x; 1.4370x over previous
//
#include <hip/hip_runtime.h>
#include <hip/hip_bf16.h>

#define FEAT 256
#define HID 128
#define CLASSES 32
#define LAYERS 3

typedef float f4 __attribute__((ext_vector_type(4)));
typedef float f2 __attribute__((ext_vector_type(2)));

// ---------------- CSR build ----------------

__global__ void count_kernel(const int* __restrict__ dst, int* __restrict__ counts, int E) {
    int e = blockIdx.x * blockDim.x + threadIdx.x;
    if (e < E) atomicAdd(&counts[dst[e]], 1);
}

// single-block shuffle-based exclusive scan: counts[N] -> row_off[N+1], cursor[N]
__global__ void scan_kernel(const int* __restrict__ counts, int* __restrict__ row_off,
                            int* __restrict__ cursor, int N) {
    __shared__ int wsum[16];
    int t = threadIdx.x;
    int lane = t & 63;
    int w = t >> 6;  // 16 waves
    int carry = 0;
    for (int base = 0; base < N; base += 1024) {
        int i = base + t;
        int v = (i < N) ? counts[i] : 0;
        int x = v;
#pragma unroll
        for (int off = 1; off < 64; off <<= 1) {
            int y = __shfl_up(x, off, 64);
            if (lane >= off) x += y;
        }
        if (lane == 63) wsum[w] = x;
        __syncthreads();
        if (w == 0) {
            int s = (lane < 16) ? wsum[lane] : 0;
#pragma unroll
            for (int off = 1; off < 16; off <<= 1) {
                int y = __shfl_up(s, off, 64);
                if (lane >= off) s += y;
            }
            if (lane < 16) wsum[lane] = s;
        }
        __syncthreads();
        int woff = (w > 0) ? wsum[w - 1] : 0;
        int excl = carry + woff + x - v;
        if (i < N) { row_off[i] = excl; cursor[i] = excl; }
        int tot = wsum[15];
        __syncthreads();
        carry += tot;
    }
    if (t == 0) row_off[N] = carry;
}

__global__ void fill_kernel(const int* __restrict__ src, const int* __restrict__ dst,
                            int* __restrict__ cursor, int* __restrict__ csr_src, int E) {
    int e = blockIdx.x * blockDim.x + threadIdx.x;
    if (e < E) {
        int pos = atomicAdd(&cursor[dst[e]], 1);
        csr_src[pos] = src[e];
    }
}

// ---------------- tiled fp32 GEMM ----------------
// out[M x NCOL] = act( concatK(A0|A1)[M x KTOT] @ concatK(W0;W1)[KTOT x NCOL] + bias )
// A split at column K0; W split at row K0 (K0 multiple of 32; K0==KTOT -> single source).
template <int NCOL, int KTOT, bool RELU>
__global__ __launch_bounds__(256) void gemm_kernel(
    const float* __restrict__ A0, int lda0,
    const float* __restrict__ A1, int lda1,
    const float* __restrict__ W0, const float* __restrict__ W1, int K0,
    const float* __restrict__ bias, float* __restrict__ out, int M) {
    constexpr int KC = 32;
    constexpr int MT = 4096 / NCOL;   // 32 (NCOL=128) or 64 (NCOL=64)
    constexpr int MTP = MT + 4;       // pad, keeps 16B alignment
    constexpr int WF4 = (KC * NCOL) / 1024;
    constexpr int AF4 = (KC * MT) / 1024;
    constexpr int NCHUNK = KTOT / KC;

    __shared__ float Wl[2][KC][NCOL];
    __shared__ float Al[2][KC][MTP];

    int t = threadIdx.x;
    int row_base = blockIdx.x * MT;
    int c0 = 4 * (t % (NCOL / 4));
    int r0 = 4 * (t / (NCOL / 4));

    f4 wreg[WF4], areg[AF4];

    auto load_chunk = [&](int kc) {
        int k0 = kc * KC;
        bool second = (k0 >= K0);
#pragma unroll
        for (int i = 0; i < WF4; ++i) {
            int idx4 = i * 256 + t;
            int kk = (idx4 * 4) / NCOL;
            int n = (idx4 * 4) % NCOL;
            int k = k0 + kk;
            const float* p = second ? (W1 + (size_t)(k - K0) * NCOL + n)
                                    : (W0 + (size_t)k * NCOL + n);
            wreg[i] = *(const f4*)p;
        }
#pragma unroll
        for (int i = 0; i < AF4; ++i) {
            int idx4 = i * 256 + t;
            int r = (idx4 * 4) / KC;
            int kk = (idx4 * 4) % KC;
            int row = row_base + r;
            int k = k0 + kk;
            if (row < M) {
                const float* p = second ? (A1 + (size_t)row * lda1 + (k - K0))
                                        : (A0 + (size_t)row * lda0 + k);
                areg[i] = *(const f4*)p;
            } else {
                areg[i] = (f4)0.f;
            }
        }
    };
    auto store_chunk = [&](int buf) {
#pragma unroll
        for (int i = 0; i < WF4; ++i) {
            int idx4 = i * 256 + t;
            int kk = (idx4 * 4) / NCOL;
            int n = (idx4 * 4) % NCOL;
            *(f4*)&Wl[buf][kk][n] = wreg[i];
        }
#pragma unroll
        for (int i = 0; i < AF4; ++i) {
            int idx4 = i * 256 + t;
            int r = (idx4 * 4) / KC;
            int kk = (idx4 * 4) % KC;
#pragma unroll
            for (int j = 0; j < 4; ++j) Al[buf][kk + j][r] = areg[i][j];
        }
    };

    float acc[4][4] = {{0.f}};
    load_chunk(0);
    store_chunk(0);
    __syncthreads();
    for (int kc = 0; kc < NCHUNK; ++kc) {
        int cur = kc & 1;
        if (kc + 1 < NCHUNK) load_chunk(kc + 1);
#pragma unroll
        for (int k = 0; k < KC; ++k) {
            f4 av = *(const f4*)&Al[cur][k][r0];
            f4 wv = *(const f4*)&Wl[cur][k][c0];
#pragma unroll
            for (int ii = 0; ii < 4; ++ii)
#pragma unroll
                for (int jj = 0; jj < 4; ++jj)
                    acc[ii][jj] = fmaf(av[ii], wv[jj], acc[ii][jj]);
        }
        if (kc + 1 < NCHUNK) {
            __syncthreads();
            store_chunk((kc + 1) & 1);
            __syncthreads();
        }
    }

    f4 bv = (f4)0.f;
    if (bias) bv = *(const f4*)&bias[c0];
#pragma unroll
    for (int ii = 0; ii < 4; ++ii) {
        int row = row_base + r0 + ii;
        if (row < M) {
            f4 o;
#pragma unroll
            for (int jj = 0; jj < 4; ++jj) {
                float v = acc[ii][jj] + bv[jj];
                o[jj] = RELU ? fmaxf(v, 0.f) : v;
            }
            *(f4*)&out[(size_t)row * NCOL + c0] = o;
        }
    }
}

// ---------------- aggregation (CSR gather-sum) ----------------
// one wave per node; lane covers 2 floats of the 128-wide row
__global__ void aggregate_kernel(const float* __restrict__ x, const int* __restrict__ row_off,
                                 const int* __restrict__ csr, float* __restrict__ agg, int N) {
    int gw = (blockIdx.x * 256 + threadIdx.x) >> 6;
    int lane = threadIdx.x & 63;
    if (gw >= N) return;
    int beg = row_off[gw], end = row_off[gw + 1];
    f2 a = (f2)0.f;
    for (int j = beg; j < end; ++j) {
        int s = csr[j];
        a += *(const f2*)&x[(size_t)s * HID + lane * 2];
    }
    *(f2*)&agg[(size_t)gw * HID + lane * 2] = a;
}

// ---------------- head ----------------
// Wpp[k][c] = head_w[k][c] (c<32) | head_w[128+k][c-32]   -> pspd = x @ Wpp  [N,64]
__global__ void wpp_kernel(const float* __restrict__ head_w, float* __restrict__ wpp) {
    int idx = blockIdx.x * blockDim.x + threadIdx.x;  // 8192 total
    int k = idx >> 6;
    int c = idx & 63;
    float v = (c < CLASSES) ? head_w[(size_t)k * CLASSES + c]
                            : head_w[(size_t)(HID + k) * CLASSES + (c - CLASSES)];
    wpp[idx] = v;
}

// out[e][c] = pspd[src[e]][c] + pspd[dst[e]][32+c] + head_b[c]
__global__ void edge_out_kernel(const int* __restrict__ src, const int* __restrict__ dst,
                                const float* __restrict__ pspd, const float* __restrict__ head_b,
                                float* __restrict__ out, int E) {
    int idx = blockIdx.x * blockDim.x + threadIdx.x;
    int e = idx >> 3;
    int c4 = (idx & 7) * 4;
    if (e >= E) return;
    int s = src[e], d = dst[e];
    f4 a = *(const f4*)&pspd[(size_t)s * 64 + c4];
    f4 b = *(const f4*)&pspd[(size_t)d * 64 + 32 + c4];
    f4 hb = *(const f4*)&head_b[c4];
    f4 o = a + b + hb;
    *(f4*)&out[(size_t)e * CLASSES + c4] = o;
}

// ---------------- launcher ----------------

extern "C" void kernel_launch(void* const* d_in, const int* in_sizes, int n_in,
                              void* d_out, int out_size, void* d_ws, size_t ws_size,
                              hipStream_t stream) {
    const float* feat   = (const float*)d_in[0];
    const int*   eidx   = (const int*)d_in[1];
    const float* emb_w  = (const float*)d_in[2];
    const float* emb_b  = (const float*)d_in[3];
    const float* rel_w  = (const float*)d_in[4];
    const float* rel_b  = (const float*)d_in[5];
    const float* root_w = (const float*)d_in[6];
    const float* head_w = (const float*)d_in[7];
    const float* head_b = (const float*)d_in[8];
    float* out = (float*)d_out;

    int N = in_sizes[0] / FEAT;
    int E = in_sizes[1] / 2;
    const int* src = eidx;
    const int* dst = eidx + E;

    // workspace layout
    float* xA      = (float*)d_ws;                       // N*HID
    float* xB      = xA + (size_t)N * HID;               // N*HID
    float* agg     = xB + (size_t)N * HID;               // N*HID (also reused as pspd[N*64])
    float* wpp     = agg + (size_t)N * HID;              // HID*64
    int*   counts  = (int*)(wpp + HID * 64);             // N
    int*   row_off = counts + N;                         // N+1
    int*   cursor  = row_off + (N + 1);                  // N
    int*   csr_src = cursor + N;                         // E

    hipMemsetAsync(counts, 0, (size_t)N * sizeof(int), stream);
    count_kernel<<<(E + 255) / 256, 256, 0, stream>>>(dst, counts, E);
    scan_kernel<<<1, 1024, 0, stream>>>(counts, row_off, cursor, N);
    fill_kernel<<<(E + 255) / 256, 256, 0, stream>>>(src, dst, cursor, csr_src, E);
    wpp_kernel<<<(HID * 64 + 255) / 256, 256, 0, stream>>>(head_w, wpp);

    int gemm128_grid = (N + 31) / 32;
    // embed: x = relu(feat @ emb_w + emb_b)
    gemm_kernel<HID, FEAT, true><<<gemm128_grid, 256, 0, stream>>>(
        feat, FEAT, nullptr, 0, emb_w, nullptr, FEAT, emb_b, xA, N);

    const float* xin = xA;
    float* xout = xB;
    for (int l = 0; l < LAYERS; ++l) {
        aggregate_kernel<<<(N * 64 + 255) / 256, 256, 0, stream>>>(xin, row_off, csr_src, agg, N);
        gemm_kernel<HID, 2 * HID, true><<<gemm128_grid, 256, 0, stream>>>(
            agg, HID, xin, HID, rel_w + (size_t)l * HID * HID, root_w + (size_t)l * HID * HID,
            HID, rel_b + (size_t)l * HID, xout, N);
        float* tmp = (float*)xin; xin = xout; xout = tmp;
    }

    // pspd = x @ Wpp  (no bias, no relu); reuse agg buffer
    float* pspd = agg;
    gemm_kernel<64, HID, false><<<(N + 63) / 64, 256, 0, stream>>>(
        xin, HID, nullptr, 0, wpp, nullptr, HID, nullptr, pspd, N);

    edge_out_kernel<<<((size_t)E * 8 + 255) / 256, 256, 0, stream>>>(src, dst, pspd, head_b, out, E);
}